// Round 16
// baseline (159.250 us; speedup 1.0000x reference)
//
#include <hip/hip_runtime.h>

#define LN_EPS 1e-5f

typedef __attribute__((ext_vector_type(8)))  short short8;
typedef __attribute__((ext_vector_type(4)))  float floatx4;
typedef __attribute__((ext_vector_type(16))) float floatx16;

__device__ __forceinline__ unsigned short f2bf(float x) {
    unsigned u = __float_as_uint(x);
    u += 0x7FFFu + ((u >> 16) & 1u);   // round-to-nearest-even
    return (unsigned short)(u >> 16);
}

// ---------------------------------------------------------------------------
// Kernel A (fused): blocks [0, nEB): per-edge MLP coords -> h B-frags (32x32),
//   counts (atomic) and rank[e].  blocks [nEB, nEB+16): W2 -> bf16 A-frags.
// B-frag (K-step t, 32-edge tile et): lane l holds col e = l&31,
// k = t*16 + (l>>5)*8 + b.  short8 idx = et*128 + t*64 + kg*32 + (e&31).
// A-frag (o, t): lane l holds row j = o*32 + (l&31), k = t*16 + (l>>5)*8 + b.
// ---------------------------------------------------------------------------
__global__ __launch_bounds__(256) void k_edge_mlp(
    const float* __restrict__ coords,
    const int*   __restrict__ target,
    const float* __restrict__ W0, const float* __restrict__ b0,
    const float* __restrict__ g0, const float* __restrict__ be0,
    const float* __restrict__ W1, const float* __restrict__ b1,
    const float* __restrict__ g1, const float* __restrict__ be1,
    const float* __restrict__ W2, unsigned short* __restrict__ w2frag,
    unsigned short* __restrict__ hfrag, int* __restrict__ counts,
    int* __restrict__ rank, int E, int nEB)
{
    const int tid = threadIdx.x;

    if (blockIdx.x >= nEB) {            // ---- W2 converter blocks ----
        const int idx = (blockIdx.x - nEB) * 256 + tid;   // 0..4095
        if (idx < 4096) {
            const int l  = idx & 63;
            const int ot = idx >> 6;
            const int t  = ot & 1;
            const int o  = ot >> 1;
            const int row = l & 31;
            const int kb  = t*16 + (l >> 5)*8;
            short8 v;
            #pragma unroll
            for (int b = 0; b < 8; ++b)
                v[b] = (short)f2bf(W2[(size_t)(kb + b)*1024 + o*32 + row]);
            ((short8*)w2frag)[idx] = v;
        }
        return;
    }

    __shared__ float sW0[3*32], sW1T[32*36];   // W1T[o][c], stride 36
    __shared__ float sb0[32], sg0[32], sbe0[32], sb1[32], sg1[32], sbe1[32];
    for (int i = tid; i < 32*32; i += 256) {
        const int o = i & 31, c = i >> 5;
        sW1T[o*36 + c] = W1[i];                // W1[c*32+o]
    }
    if (tid < 96) sW0[tid] = W0[tid];
    if (tid < 32) {
        sb0[tid] = b0[tid];  sg0[tid] = g0[tid];  sbe0[tid] = be0[tid];
        sb1[tid] = b1[tid];  sg1[tid] = g1[tid];  sbe1[tid] = be1[tid];
    }
    __syncthreads();

    const int e = blockIdx.x * 256 + tid;
    if (e >= E) return;

    const float x0 = coords[e*3+0];
    const float x1 = coords[e*3+1];
    const float x2 = coords[e*3+2];

    float h[32];
    #pragma unroll
    for (int o = 0; o < 32; ++o)
        h[o] = x0*sW0[o] + x1*sW0[32+o] + x2*sW0[64+o] + sb0[o];

    {
        float mu = 0.f;
        #pragma unroll
        for (int o = 0; o < 32; ++o) mu += h[o];
        mu *= (1.f/32.f);
        float var = 0.f;
        #pragma unroll
        for (int o = 0; o < 32; ++o) { float d = h[o]-mu; var += d*d; }
        var *= (1.f/32.f);
        const float inv = rsqrtf(var + LN_EPS);
        #pragma unroll
        for (int o = 0; o < 32; ++o)
            h[o] = fmaxf((h[o]-mu)*inv*sg0[o] + sbe0[o], 0.f);
    }

    float h2[32];
    #pragma unroll
    for (int o = 0; o < 32; ++o) {
        float s = sb1[o];
        #pragma unroll
        for (int c4 = 0; c4 < 8; ++c4) {
            const floatx4 wv = *reinterpret_cast<const floatx4*>(&sW1T[o*36 + c4*4]);
            s += h[c4*4+0]*wv[0] + h[c4*4+1]*wv[1]
               + h[c4*4+2]*wv[2] + h[c4*4+3]*wv[3];
        }
        h2[o] = s;
    }

    {
        float mu = 0.f;
        #pragma unroll
        for (int o = 0; o < 32; ++o) mu += h2[o];
        mu *= (1.f/32.f);
        float var = 0.f;
        #pragma unroll
        for (int o = 0; o < 32; ++o) { float d = h2[o]-mu; var += d*d; }
        var *= (1.f/32.f);
        const float inv = rsqrtf(var + LN_EPS);
        #pragma unroll
        for (int o = 0; o < 32; ++o)
            h2[o] = fmaxf((h2[o]-mu)*inv*sg1[o] + sbe1[o], 0.f);
    }

    const int et = e >> 5, er = e & 31;
    short8* base = (short8*)(hfrag) + (size_t)et * 128;
    #pragma unroll
    for (int t = 0; t < 2; ++t) {
        #pragma unroll
        for (int kg = 0; kg < 2; ++kg) {
            short8 v;
            #pragma unroll
            for (int b = 0; b < 8; ++b) v[b] = (short)f2bf(h2[t*16 + kg*8 + b]);
            base[t*64 + kg*32 + er] = v;
        }
    }

    rank[e] = atomicAdd(&counts[target[e]], 1);
}

// ---------------------------------------------------------------------------
// Kernel scan: exclusive prefix sum of counts[N] -> offs[N+1].
// ---------------------------------------------------------------------------
__global__ __launch_bounds__(1024) void k_scan(
    const int* __restrict__ counts, int* __restrict__ offs, int N)
{
    __shared__ int wsum[16];
    const int t = threadIdx.x;
    const int lane = t & 63, w = t >> 6;
    const int CH = (N + 1023) >> 10;
    const int beg = t * CH;

    int s = 0;
    for (int k = 0; k < CH; ++k) {
        const int i = beg + k;
        if (i < N) s += counts[i];
    }
    int incl = s;
    #pragma unroll
    for (int d = 1; d < 64; d <<= 1) {
        const int x = __shfl_up(incl, d);
        if (lane >= d) incl += x;
    }
    if (lane == 63) wsum[w] = incl;
    __syncthreads();
    if (t == 0) {
        int run = 0;
        #pragma unroll
        for (int i = 0; i < 16; ++i) { const int v = wsum[i]; wsum[i] = run; run += v; }
    }
    __syncthreads();
    const int base = wsum[w] + incl - s;
    int run = base;
    for (int k = 0; k < CH; ++k) {
        const int i = beg + k;
        if (i < N) { offs[i] = run; run += counts[i]; }
    }
    if (t == 1023) offs[N] = base + s;
}

// Per-unit compute macro: MFMA pair + tanh-folded epilogue -> q[4]
#define FIELD_COMPUTE(BS0, BS1, FV, FSL, QOUT)                                 \
    {                                                                          \
        _Pragma("unroll")                                                      \
        for (int u = 0; u < 4; ++u) {                                          \
            floatx16 d = __builtin_amdgcn_mfma_f32_32x32x16_bf16(afr[2*u],   (BS0), z16, 0, 0, 0); \
            d          = __builtin_amdgcn_mfma_f32_32x32x16_bf16(afr[2*u+1], (BS1), d,   0, 0, 0); \
            float sf0 = 0.f, sf1 = 0.f, sf2 = 0.f, sf3 = 0.f;                  \
            _Pragma("unroll")                                                  \
            for (int qq = 0; qq < 4; ++qq) {                                   \
                const floatx4 bq = *reinterpret_cast<const floatx4*>(b2base + u*32 + 8*qq); \
                const float t0 = fmaf((FV)[qq][0]*0.f + d[qq*4+0], KE, bq[0]); \
                sf0 = fmaf((FV)[qq][0], __builtin_amdgcn_rcpf(__builtin_amdgcn_exp2f(t0) + 1.0f), sf0); \
                const float t1 = fmaf(d[qq*4+1], KE, bq[1]);                   \
                sf1 = fmaf((FV)[qq][1], __builtin_amdgcn_rcpf(__builtin_amdgcn_exp2f(t1) + 1.0f), sf1); \
                const float t2 = fmaf(d[qq*4+2], KE, bq[2]);                   \
                sf2 = fmaf((FV)[qq][2], __builtin_amdgcn_rcpf(__builtin_amdgcn_exp2f(t2) + 1.0f), sf2); \
                const float t3 = fmaf(d[qq*4+3], KE, bq[3]);                   \
                sf3 = fmaf((FV)[qq][3], __builtin_amdgcn_rcpf(__builtin_amdgcn_exp2f(t3) + 1.0f), sf3); \
            }                                                                  \
            const float sf = (sf0 + sf1) + (sf2 + sf3);                        \
            const float v  = fmaf(-2.0f, sf, (FSL));                           \
            (QOUT)[u] = v + __shfl_xor(v, 32);                                 \
        }                                                                      \
    }

// ---------------------------------------------------------------------------
// Kernel B: 32x32x16 MFMA, D = W2T_tile @ h_tile.  256-thread blocks (4 waves),
// 2 blocks per edge-tile (jh = blockIdx&1; gridDim EVEN so jh block-uniform).
// Round-16 change vs round 10: 2-DEEP UNIT PIPELINE per barrier interval.
// Each iteration processes units (unit, unit+gridDim) — same jh parity.
// All loads for BOTH units issue at the top (2x memory-level parallelism per
// wave; round-12's cross-barrier prefetch failed because the barrier drained
// it — here both units complete before the single shared barrier). Barrier
// count halves. (256,2): VGPR cap 128, est ~115, no spill.
// ---------------------------------------------------------------------------
__global__ __launch_bounds__(256, 2) void k_field_mfma(
    const unsigned short* __restrict__ hfrag,
    const unsigned short* __restrict__ w2frag,
    const float* __restrict__ features,
    const int*   __restrict__ src,
    const int*   __restrict__ tgt,
    const int*   __restrict__ rank,
    const int*   __restrict__ offs,
    const float* __restrict__ b2,
    unsigned short* __restrict__ ocP,
    int netiles)
{
    __shared__ float s_b2s[1024];
    __shared__ unsigned int sOC[2][2][32*9];   // [buf][unit-half][row*9+dword]
    __shared__ int sP[2][64];
    const int tid = threadIdx.x;
    const float KE = 2.8853900817779268f;   // 2*log2(e)
    #pragma unroll
    for (int r = 0; r < 4; ++r) s_b2s[tid + 256*r] = KE * b2[tid + 256*r];

    const int lane = tid & 63;
    const int wq   = tid >> 6;              // 0..3 wave in block
    const int jh   = blockIdx.x & 1;        // j-half (gridDim EVEN)
    const int W    = jh*4 + wq;             // 0..7 o-block (o = W*4+u)
    const int h5   = lane >> 5;
    const int ecol = lane & 31;
    const float* b2base = &s_b2s[W*128 + 4*h5];
    const int str = tid >> 2;               // store-pass row 0..63
    const int sti = (tid & 3) * 2;          // store-pass dword pair 0..6

    // resident W2 A-frags: 8 x short8 = 32 VGPR
    short8 afr[8];
    #pragma unroll
    for (int u = 0; u < 8; ++u)
        afr[u] = ((const short8*)w2frag)[(W*8 + u)*64 + lane];
    __syncthreads();

    const floatx16 z16 = {0.f,0.f,0.f,0.f,0.f,0.f,0.f,0.f,
                          0.f,0.f,0.f,0.f,0.f,0.f,0.f,0.f};

    const int nunits = 2*netiles;
    const int g = gridDim.x;
    int buf = 0;
    for (int unit = blockIdx.x; unit < nunits; unit += 2*g, buf ^= 1) {
        const int unitB = unit + g;
        const bool hasB = (unitB < nunits);   // block-uniform
        const int etA = unit >> 1;
        const int e0A = etA << 5;
        const int etB = (hasB ? unitB : unit) >> 1;
        const int e0B = etB << 5;

        // ---- all loads for both units issue here ----
        const short8 bsA0 = ((const short8*)hfrag)[etA*128 + lane];
        const short8 bsA1 = ((const short8*)hfrag)[etA*128 + 64 + lane];
        const short8 bsB0 = ((const short8*)hfrag)[etB*128 + lane];
        const short8 bsB1 = ((const short8*)hfrag)[etB*128 + 64 + lane];
        const int sNA = src[e0A + ecol];
        const int sNB = src[e0B + ecol];
        if (tid < 32) {
            sP[buf][ecol]      = offs[tgt[e0A + ecol]] + rank[e0A + ecol];
            sP[buf][32 + ecol] = offs[tgt[e0B + ecol]] + rank[e0B + ecol];
        }

        floatx4 fvA[4], fvB[4];
        float fslA = 0.f, fslB = 0.f;
        #pragma unroll
        for (int rq = 0; rq < 4; ++rq) {
            fvA[rq] = *reinterpret_cast<const floatx4*>(
                          features + (size_t)sNA*32 + rq*8 + 4*h5);
            fvB[rq] = *reinterpret_cast<const floatx4*>(
                          features + (size_t)sNB*32 + rq*8 + 4*h5);
            #pragma unroll
            for (int rr = 0; rr < 4; ++rr) {
                fslA += fvA[rq][rr];
                fslB += fvB[rq][rr];
            }
        }

        // ---- compute A, then B ----
        float qA[4], qB[4];
        FIELD_COMPUTE(bsA0, bsA1, fvA, fslA, qA);
        FIELD_COMPUTE(bsB0, bsB1, fvB, fslB, qB);

        if (lane < 32) {
            sOC[buf][0][ecol*9 + wq*2]     = ((unsigned)f2bf(qA[1]) << 16) | f2bf(qA[0]);
            sOC[buf][0][ecol*9 + wq*2 + 1] = ((unsigned)f2bf(qA[3]) << 16) | f2bf(qA[2]);
            sOC[buf][1][ecol*9 + wq*2]     = ((unsigned)f2bf(qB[1]) << 16) | f2bf(qB[0]);
            sOC[buf][1][ecol*9 + wq*2 + 1] = ((unsigned)f2bf(qB[3]) << 16) | f2bf(qB[2]);
        }
        __syncthreads();
        // store pass: 64 rows x 8 dwords; 4 threads/row, 8B contiguous each
        {
            const int uh = str >> 5, r32 = str & 31;
            if (uh == 0 || hasB) {
                const unsigned v0 = sOC[buf][uh][r32*9 + sti];
                const unsigned v1 = sOC[buf][uh][r32*9 + sti + 1];
                unsigned* dst = (unsigned*)ocP + (size_t)sP[buf][str]*16 + jh*8 + sti;
                dst[0] = v0;
                dst[1] = v1;
            }
        }
        // no trailing barrier: double-buffered; this buf re-written only
        // after the NEXT iteration's barrier.
    }
}

// ---------------------------------------------------------------------------
// Kernel gather: CSR rows of ocP (target-sorted), mean, write out.
// ---------------------------------------------------------------------------
__global__ __launch_bounds__(256) void k_gather(
    const unsigned short* __restrict__ ocP,
    const int* __restrict__ offs,
    float* __restrict__ out, int N)
{
    const int node = blockIdx.x * 4 + (threadIdx.x >> 6);
    const int lane = threadIdx.x & 63;
    if (node >= N) return;
    const int r = lane >> 3;        // 0..7  row stagger
    const int c = lane & 7;         // 0..7  o-chunk (4 shorts)
    const int beg = offs[node], end = offs[node + 1];

    float a0 = 0.f, a1 = 0.f, a2 = 0.f, a3 = 0.f;
    for (int k = beg + r; k < end; k += 8) {
        const uint2 v = *reinterpret_cast<const uint2*>(ocP + (size_t)k*32 + c*4);
        a0 += __uint_as_float(v.x << 16);
        a1 += __uint_as_float(v.x & 0xFFFF0000u);
        a2 += __uint_as_float(v.y << 16);
        a3 += __uint_as_float(v.y & 0xFFFF0000u);
    }
    #pragma unroll
    for (int m = 8; m < 64; m <<= 1) {
        a0 += __shfl_xor(a0, m);
        a1 += __shfl_xor(a1, m);
        a2 += __shfl_xor(a2, m);
        a3 += __shfl_xor(a3, m);
    }
    if (lane < 8) {
        const float rinv = __builtin_amdgcn_rcpf(fmaxf((float)(end - beg), 1.0f));
        floatx4 o4 = {a0*rinv, a1*rinv, a2*rinv, a3*rinv};
        *reinterpret_cast<floatx4*>(out + (size_t)node*32 + lane*4) = o4;
    }
}

// ---------------------------------------------------------------------------
extern "C" void kernel_launch(void* const* d_in, const int* in_sizes, int n_in,
                              void* d_out, int out_size, void* d_ws, size_t ws_size,
                              hipStream_t stream)
{
    const float* features = (const float*)d_in[0];
    const float* coords   = (const float*)d_in[1];
    const int*   src      = (const int*)  d_in[2];
    const int*   tgt      = (const int*)  d_in[3];
    const float* W0  = (const float*)d_in[4];
    const float* b0  = (const float*)d_in[5];
    const float* g0  = (const float*)d_in[6];
    const float* be0 = (const float*)d_in[7];
    const float* W1  = (const float*)d_in[8];
    const float* b1  = (const float*)d_in[9];
    const float* g1  = (const float*)d_in[10];
    const float* be1 = (const float*)d_in[11];
    const float* W2  = (const float*)d_in[12];
    const float* b2  = (const float*)d_in[13];

    const int E = in_sizes[2];           // 160000 (multiple of 32)
    const int N = in_sizes[0] / 32;      // 10000

    char* p = (char*)d_ws;
    unsigned short* hfrag  = (unsigned short*)p;  p += (size_t)E*32*2;   // 10.24 MB
    unsigned short* ocP    = (unsigned short*)p;  p += (size_t)E*32*2;   // 10.24 MB
    unsigned short* w2frag = (unsigned short*)p;  p += 32*1024*2;        // 64 KB
    int* rankArr = (int*)p;  p += (size_t)E*4;                           // 640 KB
    int* counts  = (int*)p;  p += (size_t)N*4;
    int* offs    = (int*)p;  p += (size_t)(N+1)*4;

    (void)hipMemsetAsync(counts, 0, (size_t)N*4, stream);

    const int nEB = (E + 255)/256;       // 625 edge blocks + 16 w2 blocks
    k_edge_mlp<<<nEB + 16, 256, 0, stream>>>(
        coords, tgt, W0, b0, g0, be0, W1, b1, g1, be1, W2, w2frag,
        hfrag, counts, rankArr, E, nEB);

    k_scan<<<1, 1024, 0, stream>>>(counts, offs, N);

    const int netiles = E / 32;          // 5000 -> nunits 10000
    k_field_mfma<<<2048, 256, 0, stream>>>(
        hfrag, w2frag, features, src, tgt, rankArr, offs, b2, ocP, netiles);

    k_gather<<<(N + 3)/4, 256, 0, stream>>>(ocP, offs, (float*)d_out, N);
}

// Round 17
// 99.094 us; speedup vs baseline: 1.6071x; 1.6071x over previous
//
#include <hip/hip_runtime.h>

#define LN_EPS 1e-5f

typedef __attribute__((ext_vector_type(8)))  short short8;
typedef __attribute__((ext_vector_type(4)))  float floatx4;
typedef __attribute__((ext_vector_type(16))) float floatx16;

__device__ __forceinline__ unsigned short f2bf(float x) {
    unsigned u = __float_as_uint(x);
    u += 0x7FFFu + ((u >> 16) & 1u);   // round-to-nearest-even
    return (unsigned short)(u >> 16);
}

// ---------------------------------------------------------------------------
// Kernel A (fused): blocks [0, nEB): per-edge MLP coords -> h B-frags,
//   counts (atomic) and rank[e].  blocks [nEB, nEB+16): W2 -> bf16 A-frags.
// B-frag (K-step t, 32-edge tile et): lane l holds col e = l&31,
// k = t*16 + (l>>5)*8 + b.  short8 idx = et*128 + t*64 + kg*32 + (e&31).
// A-frag (o, t): lane l holds row j = o*32 + (l&31), k = t*16 + (l>>5)*8 + b.
// ---------------------------------------------------------------------------
__global__ __launch_bounds__(256) void k_edge_mlp(
    const float* __restrict__ coords,
    const int*   __restrict__ target,
    const float* __restrict__ W0, const float* __restrict__ b0,
    const float* __restrict__ g0, const float* __restrict__ be0,
    const float* __restrict__ W1, const float* __restrict__ b1,
    const float* __restrict__ g1, const float* __restrict__ be1,
    const float* __restrict__ W2, unsigned short* __restrict__ w2frag,
    unsigned short* __restrict__ hfrag, int* __restrict__ counts,
    int* __restrict__ rank, int E, int nEB)
{
    const int tid = threadIdx.x;

    if (blockIdx.x >= nEB) {            // ---- W2 converter blocks ----
        const int idx = (blockIdx.x - nEB) * 256 + tid;   // 0..4095
        if (idx < 4096) {
            const int l  = idx & 63;
            const int ot = idx >> 6;
            const int t  = ot & 1;
            const int o  = ot >> 1;
            const int row = l & 31;
            const int kb  = t*16 + (l >> 5)*8;
            short8 v;
            #pragma unroll
            for (int b = 0; b < 8; ++b)
                v[b] = (short)f2bf(W2[(size_t)(kb + b)*1024 + o*32 + row]);
            ((short8*)w2frag)[idx] = v;
        }
        return;
    }

    __shared__ float sW0[3*32], sW1T[32*36];   // W1T[o][c], stride 36
    __shared__ float sb0[32], sg0[32], sbe0[32], sb1[32], sg1[32], sbe1[32];
    for (int i = tid; i < 32*32; i += 256) {
        const int o = i & 31, c = i >> 5;
        sW1T[o*36 + c] = W1[i];                // W1[c*32+o]
    }
    if (tid < 96) sW0[tid] = W0[tid];
    if (tid < 32) {
        sb0[tid] = b0[tid];  sg0[tid] = g0[tid];  sbe0[tid] = be0[tid];
        sb1[tid] = b1[tid];  sg1[tid] = g1[tid];  sbe1[tid] = be1[tid];
    }
    __syncthreads();

    const int e = blockIdx.x * 256 + tid;
    if (e >= E) return;

    const float x0 = coords[e*3+0];
    const float x1 = coords[e*3+1];
    const float x2 = coords[e*3+2];

    float h[32];
    #pragma unroll
    for (int o = 0; o < 32; ++o)
        h[o] = x0*sW0[o] + x1*sW0[32+o] + x2*sW0[64+o] + sb0[o];

    {
        float mu = 0.f;
        #pragma unroll
        for (int o = 0; o < 32; ++o) mu += h[o];
        mu *= (1.f/32.f);
        float var = 0.f;
        #pragma unroll
        for (int o = 0; o < 32; ++o) { float d = h[o]-mu; var += d*d; }
        var *= (1.f/32.f);
        const float inv = rsqrtf(var + LN_EPS);
        #pragma unroll
        for (int o = 0; o < 32; ++o)
            h[o] = fmaxf((h[o]-mu)*inv*sg0[o] + sbe0[o], 0.f);
    }

    float h2[32];
    #pragma unroll
    for (int o = 0; o < 32; ++o) {
        float s = sb1[o];
        #pragma unroll
        for (int c4 = 0; c4 < 8; ++c4) {
            const floatx4 wv = *reinterpret_cast<const floatx4*>(&sW1T[o*36 + c4*4]);
            s += h[c4*4+0]*wv[0] + h[c4*4+1]*wv[1]
               + h[c4*4+2]*wv[2] + h[c4*4+3]*wv[3];
        }
        h2[o] = s;
    }

    {
        float mu = 0.f;
        #pragma unroll
        for (int o = 0; o < 32; ++o) mu += h2[o];
        mu *= (1.f/32.f);
        float var = 0.f;
        #pragma unroll
        for (int o = 0; o < 32; ++o) { float d = h2[o]-mu; var += d*d; }
        var *= (1.f/32.f);
        const float inv = rsqrtf(var + LN_EPS);
        #pragma unroll
        for (int o = 0; o < 32; ++o)
            h2[o] = fmaxf((h2[o]-mu)*inv*sg1[o] + sbe1[o], 0.f);
    }

    const int et = e >> 5, er = e & 31;
    short8* base = (short8*)(hfrag) + (size_t)et * 128;
    #pragma unroll
    for (int t = 0; t < 2; ++t) {
        #pragma unroll
        for (int kg = 0; kg < 2; ++kg) {
            short8 v;
            #pragma unroll
            for (int b = 0; b < 8; ++b) v[b] = (short)f2bf(h2[t*16 + kg*8 + b]);
            base[t*64 + kg*32 + er] = v;
        }
    }

    rank[e] = atomicAdd(&counts[target[e]], 1);
}

// ---------------------------------------------------------------------------
// Kernel scan: exclusive prefix sum of counts[N] -> offs[N+1].
// Round-17: counts staged to LDS with coalesced stride-1024 loads; scan from
// LDS; results written back to LDS then stored coalesced. (Old version did
// 10 uncoalesced passes at 40B thread-stride both directions.)
// ---------------------------------------------------------------------------
__global__ __launch_bounds__(1024) void k_scan(
    const int* __restrict__ counts, int* __restrict__ offs, int N)
{
    __shared__ int sC[10240];
    __shared__ int wsum[16];
    const int t = threadIdx.x;
    const int lane = t & 63, w = t >> 6;
    const int CH = (N + 1023) >> 10;

    for (int i = t; i < N; i += 1024) sC[i] = counts[i];    // coalesced in
    __syncthreads();

    const int beg = t * CH;
    int s = 0;
    #pragma unroll 4
    for (int k = 0; k < CH; ++k) {
        const int i = beg + k;
        if (i < N) s += sC[i];
    }
    int incl = s;
    #pragma unroll
    for (int d = 1; d < 64; d <<= 1) {
        const int x = __shfl_up(incl, d);
        if (lane >= d) incl += x;
    }
    if (lane == 63) wsum[w] = incl;
    __syncthreads();
    if (t == 0) {
        int run = 0;
        #pragma unroll
        for (int i = 0; i < 16; ++i) { const int v = wsum[i]; wsum[i] = run; run += v; }
    }
    __syncthreads();
    const int base = wsum[w] + incl - s;
    int run = base;
    // overwrite own chunk in place (all reads of this chunk happened above)
    #pragma unroll 4
    for (int k = 0; k < CH; ++k) {
        const int i = beg + k;
        if (i < N) { const int c = sC[i]; sC[i] = run; run += c; }
    }
    __syncthreads();
    for (int i = t; i < N; i += 1024) offs[i] = sC[i];      // coalesced out
    if (t == 1023) offs[N] = base + s;
}

// ---------------------------------------------------------------------------
// Kernel B: 32x32x16 MFMA, D = W2T_tile @ h_tile.  256-thread blocks (4 waves),
// 2 blocks per edge-tile (jh = blockIdx&1; gridDim EVEN so jh block-uniform).
// Round-17: (256,3) — cap 256/3=84 >= the ~68-reg live set (no spill), but
// blocks the allocator's inflate-to-cap (round 16: offered 128, used 128).
// Measured caps: w=2/3/4/6/8 -> 128/84/64/40/32 (rounds 5-16).
// Epilogue: t = fma(d, KE, KE*b2) [LDS]; r = rcp(exp2(t)+1);
//   oc[e,o] = fsum - 2*sum(f*r)  (tanh folded), 4 partial accumulators.
// CSR slot p = offs[tgt[e]] + rank[e].  sOC double-buffered -> ONE barrier/unit.
// ---------------------------------------------------------------------------
__global__ __launch_bounds__(256, 3) void k_field_mfma(
    const unsigned short* __restrict__ hfrag,
    const unsigned short* __restrict__ w2frag,
    const float* __restrict__ features,
    const int*   __restrict__ src,
    const int*   __restrict__ tgt,
    const int*   __restrict__ rank,
    const int*   __restrict__ offs,
    const float* __restrict__ b2,
    unsigned short* __restrict__ ocP,
    int netiles)
{
    __shared__ float s_b2s[1024];
    __shared__ unsigned int sOC[2][32*9];   // 32 rows x 8 dwords, stride 9
    __shared__ int sP[2][32];
    const int tid = threadIdx.x;
    const float KE = 2.8853900817779268f;   // 2*log2(e)
    #pragma unroll
    for (int r = 0; r < 4; ++r) s_b2s[tid + 256*r] = KE * b2[tid + 256*r];

    const int lane = tid & 63;
    const int wq   = tid >> 6;              // 0..3 wave in block
    const int jh   = blockIdx.x & 1;        // j-half (gridDim EVEN)
    const int W    = jh*4 + wq;             // 0..7 o-block (o = W*4+u)
    const int h5   = lane >> 5;
    const int ecol = lane & 31;
    const float* b2base = &s_b2s[W*128 + 4*h5];
    const int str = tid >> 3;               // store-pass row 0..31
    const int sti = tid & 7;                // store-pass dword 0..7

    // resident W2 A-frags: 8 x short8 = 32 VGPR
    short8 afr[8];
    #pragma unroll
    for (int u = 0; u < 8; ++u)
        afr[u] = ((const short8*)w2frag)[(W*8 + u)*64 + lane];
    __syncthreads();

    const floatx16 z16 = {0.f,0.f,0.f,0.f,0.f,0.f,0.f,0.f,
                          0.f,0.f,0.f,0.f,0.f,0.f,0.f,0.f};

    const int nunits = 2*netiles;
    int buf = 0;
    for (int unit = blockIdx.x; unit < nunits; unit += gridDim.x, buf ^= 1) {
        const int et = unit >> 1;
        const int e0 = et << 5;
        const short8 bs0 = ((const short8*)hfrag)[et*128 + lane];
        const short8 bs1 = ((const short8*)hfrag)[et*128 + 64 + lane];

        const int sN = src[e0 + ecol];
        if (tid < 32) sP[buf][ecol] = offs[tgt[e0 + ecol]] + rank[e0 + ecol];

        floatx4 fv[4];
        float fsl = 0.f;
        #pragma unroll
        for (int rq = 0; rq < 4; ++rq) {
            fv[rq] = *reinterpret_cast<const floatx4*>(
                         features + (size_t)sN*32 + rq*8 + 4*h5);
            #pragma unroll
            for (int rr = 0; rr < 4; ++rr) fsl += fv[rq][rr];
        }

        float q[4];
        #pragma unroll
        for (int u = 0; u < 4; ++u) {
            floatx16 d = __builtin_amdgcn_mfma_f32_32x32x16_bf16(afr[2*u],   bs0, z16, 0, 0, 0);
            d          = __builtin_amdgcn_mfma_f32_32x32x16_bf16(afr[2*u+1], bs1, d,   0, 0, 0);
            float sf0 = 0.f, sf1 = 0.f, sf2 = 0.f, sf3 = 0.f;
            #pragma unroll
            for (int qq = 0; qq < 4; ++qq) {
                const floatx4 bq = *reinterpret_cast<const floatx4*>(b2base + u*32 + 8*qq);
                const float t0 = fmaf(d[qq*4+0], KE, bq[0]);
                sf0 = fmaf(fv[qq][0], __builtin_amdgcn_rcpf(__builtin_amdgcn_exp2f(t0) + 1.0f), sf0);
                const float t1 = fmaf(d[qq*4+1], KE, bq[1]);
                sf1 = fmaf(fv[qq][1], __builtin_amdgcn_rcpf(__builtin_amdgcn_exp2f(t1) + 1.0f), sf1);
                const float t2 = fmaf(d[qq*4+2], KE, bq[2]);
                sf2 = fmaf(fv[qq][2], __builtin_amdgcn_rcpf(__builtin_amdgcn_exp2f(t2) + 1.0f), sf2);
                const float t3 = fmaf(d[qq*4+3], KE, bq[3]);
                sf3 = fmaf(fv[qq][3], __builtin_amdgcn_rcpf(__builtin_amdgcn_exp2f(t3) + 1.0f), sf3);
            }
            const float sf = (sf0 + sf1) + (sf2 + sf3);
            const float v  = fmaf(-2.0f, sf, fsl);   // lane-half of fsum - 2*sum(f*r)
            q[u] = v + __shfl_xor(v, 32);
        }

        if (lane < 32) {
            const unsigned d0 = ((unsigned)f2bf(q[1]) << 16) | f2bf(q[0]);
            const unsigned d1 = ((unsigned)f2bf(q[3]) << 16) | f2bf(q[2]);
            sOC[buf][ecol*9 + wq*2]     = d0;
            sOC[buf][ecol*9 + wq*2 + 1] = d1;
        }
        __syncthreads();
        // store pass: 8 lanes/row -> one contiguous 32B store per row-half
        ((unsigned int*)ocP)[(size_t)sP[buf][str]*16 + jh*8 + sti] = sOC[buf][str*9 + sti];
        // no trailing barrier: double-buffered; this buf re-written only
        // after the NEXT iteration's barrier.
    }
}

// ---------------------------------------------------------------------------
// Kernel gather: CSR rows of ocP (target-sorted), mean, write out.
// ---------------------------------------------------------------------------
__global__ __launch_bounds__(256) void k_gather(
    const unsigned short* __restrict__ ocP,
    const int* __restrict__ offs,
    float* __restrict__ out, int N)
{
    const int node = blockIdx.x * 4 + (threadIdx.x >> 6);
    const int lane = threadIdx.x & 63;
    if (node >= N) return;
    const int r = lane >> 3;        // 0..7  row stagger
    const int c = lane & 7;         // 0..7  o-chunk (4 shorts)
    const int beg = offs[node], end = offs[node + 1];

    float a0 = 0.f, a1 = 0.f, a2 = 0.f, a3 = 0.f;
    for (int k = beg + r; k < end; k += 8) {
        const uint2 v = *reinterpret_cast<const uint2*>(ocP + (size_t)k*32 + c*4);
        a0 += __uint_as_float(v.x << 16);
        a1 += __uint_as_float(v.x & 0xFFFF0000u);
        a2 += __uint_as_float(v.y << 16);
        a3 += __uint_as_float(v.y & 0xFFFF0000u);
    }
    #pragma unroll
    for (int m = 8; m < 64; m <<= 1) {
        a0 += __shfl_xor(a0, m);
        a1 += __shfl_xor(a1, m);
        a2 += __shfl_xor(a2, m);
        a3 += __shfl_xor(a3, m);
    }
    if (lane < 8) {
        const float rinv = __builtin_amdgcn_rcpf(fmaxf((float)(end - beg), 1.0f));
        floatx4 o4 = {a0*rinv, a1*rinv, a2*rinv, a3*rinv};
        *reinterpret_cast<floatx4*>(out + (size_t)node*32 + lane*4) = o4;
    }
}

// ---------------------------------------------------------------------------
extern "C" void kernel_launch(void* const* d_in, const int* in_sizes, int n_in,
                              void* d_out, int out_size, void* d_ws, size_t ws_size,
                              hipStream_t stream)
{
    const float* features = (const float*)d_in[0];
    const float* coords   = (const float*)d_in[1];
    const int*   src      = (const int*)  d_in[2];
    const int*   tgt      = (const int*)  d_in[3];
    const float* W0  = (const float*)d_in[4];
    const float* b0  = (const float*)d_in[5];
    const float* g0  = (const float*)d_in[6];
    const float* be0 = (const float*)d_in[7];
    const float* W1  = (const float*)d_in[8];
    const float* b1  = (const float*)d_in[9];
    const float* g1  = (const float*)d_in[10];
    const float* be1 = (const float*)d_in[11];
    const float* W2  = (const float*)d_in[12];
    const float* b2  = (const float*)d_in[13];

    const int E = in_sizes[2];           // 160000 (multiple of 32)
    const int N = in_sizes[0] / 32;      // 10000

    char* p = (char*)d_ws;
    unsigned short* hfrag  = (unsigned short*)p;  p += (size_t)E*32*2;   // 10.24 MB
    unsigned short* ocP    = (unsigned short*)p;  p += (size_t)E*32*2;   // 10.24 MB
    unsigned short* w2frag = (unsigned short*)p;  p += 32*1024*2;        // 64 KB
    int* rankArr = (int*)p;  p += (size_t)E*4;                           // 640 KB
    int* counts  = (int*)p;  p += (size_t)N*4;
    int* offs    = (int*)p;  p += (size_t)(N+1)*4;

    (void)hipMemsetAsync(counts, 0, (size_t)N*4, stream);

    const int nEB = (E + 255)/256;       // 625 edge blocks + 16 w2 blocks
    k_edge_mlp<<<nEB + 16, 256, 0, stream>>>(
        coords, tgt, W0, b0, g0, be0, W1, b1, g1, be1, W2, w2frag,
        hfrag, counts, rankArr, E, nEB);

    k_scan<<<1, 1024, 0, stream>>>(counts, offs, N);

    const int netiles = E / 32;          // 5000
    k_field_mfma<<<2048, 256, 0, stream>>>(
        hfrag, w2frag, features, src, tgt, rankArr, offs, b2, ocP, netiles);

    k_gather<<<(N + 3)/4, 256, 0, stream>>>(ocP, offs, (float*)d_out, N);
}